// Round 10
// baseline (108.938 us; speedup 1.0000x reference)
//
#include <hip/hip_runtime.h>

// MoP fused kernel for MI355X (gfx950).
// B=65536, OBS=256, GOAL=64, S=16, H=128, A=32.
// d_out = [mixed (B*32 f32)] ++ [alphas (B*16 f32)]
// R10: R7's M-split (wave pairs share 64 rows; halves of h) with
// __launch_bounds__(512,1): no forced 256-reg cap -> allocator takes ~225
// regs WITHOUT spilling; occupancy lands at 2 waves/SIMD naturally
// (2 x ~230 <= 512-reg SIMD pool). R6/R7/R9 all spilled because the
// forced min-occupancy cap made the allocator split/spill (R4 precedent:
// launch_bounds(256,1) -> VGPR=240, zero spill).

typedef __attribute__((ext_vector_type(8))) short    bf16x8;  // 8 bf16, 4 VGPR
typedef __attribute__((ext_vector_type(4))) float    f32x4;
typedef __attribute__((ext_vector_type(4))) _Float16 f16x4;
using half2v = decltype(__builtin_amdgcn_cvt_pkrtz(0.f, 0.f));  // __fp16 x2

// ---- gate image (XOR-swizzled W, one-time use) ----
#define GATE_W1_OFF   0        // Wa1^T bf16: 128 rows x 640 B = 81920
#define GATE_W2_OFF   81920    // Wa2^T f16: 16 rows x 256 B = 4096
#define GATE_BA1_OFF  86016    // ba1 f32[128] = 512
#define GATE_BA2_OFF  86528    // ba2 f32[16]  = 64
#define GATE_BYTES    86592
// ---- skill images (pad-based, immediate-offset reads) ----
#define S_W1_STRIDE   528      // 128 rows -> 67584 B
#define S_W2_OFF      67584    // 32 rows x 272 B = 8704
#define S_W2_STRIDE   272
#define S_B1_OFF      76288    // b1 f32[128] = 512
#define S_B2_OFF      76800    // b2 f32[32]  = 128
#define S_IMG         76928
#define LDS_BYTES     163520   // bufA [0,86592) gate/odd skills, bufB [86592,+76928) even

__device__ __forceinline__ unsigned short f2bf(float f) {
  unsigned u = __builtin_bit_cast(unsigned, f);
  return (unsigned short)((u + 0x7FFFu + ((u >> 16) & 1u)) >> 16);  // RNE
}

__device__ __forceinline__ bf16x8 pack_bf8(f32x4 a, f32x4 b) {
  int4 r;
  asm("v_cvt_pk_bf16_f32 %0, %1, %2" : "=v"(r.x) : "v"(a[0]), "v"(a[1]));
  asm("v_cvt_pk_bf16_f32 %0, %1, %2" : "=v"(r.y) : "v"(a[2]), "v"(a[3]));
  asm("v_cvt_pk_bf16_f32 %0, %1, %2" : "=v"(r.z) : "v"(b[0]), "v"(b[1]));
  asm("v_cvt_pk_bf16_f32 %0, %1, %2" : "=v"(r.w) : "v"(b[2]), "v"(b[3]));
  return __builtin_bit_cast(bf16x8, r);
}

#define RELU_SCALE_PACK(dst, v, av, z)                                   \
  {                                                                      \
    half2v lo_ = __builtin_amdgcn_cvt_pkrtz((v)[0], (v)[1]);             \
    half2v hi_ = __builtin_amdgcn_cvt_pkrtz((v)[2], (v)[3]);             \
    lo_ = __builtin_elementwise_max(lo_, z) * (av);                      \
    hi_ = __builtin_elementwise_max(hi_, z) * (av);                      \
    dst[0] = (_Float16)lo_[0]; dst[1] = (_Float16)lo_[1];                \
    dst[2] = (_Float16)hi_[0]; dst[3] = (_Float16)hi_[1];                \
  }
#define RELU_PACK(dst, v, z)                                             \
  {                                                                      \
    half2v lo_ = __builtin_amdgcn_cvt_pkrtz((v)[0], (v)[1]);             \
    half2v hi_ = __builtin_amdgcn_cvt_pkrtz((v)[2], (v)[3]);             \
    lo_ = __builtin_elementwise_max(lo_, z);                             \
    hi_ = __builtin_elementwise_max(hi_, z);                             \
    dst[0] = (_Float16)lo_[0]; dst[1] = (_Float16)lo_[1];                \
    dst[2] = (_Float16)hi_[0]; dst[3] = (_Float16)hi_[1];                \
  }

// ---------------- weight prep: f32 -> bf16/f16 LDS images in ws -------------
__global__ void prep_weights(const float* __restrict__ Wa1, const float* __restrict__ Wa2,
                             const float* __restrict__ ba1, const float* __restrict__ ba2,
                             const float* __restrict__ W1,  const float* __restrict__ W2,
                             const float* __restrict__ b1,  const float* __restrict__ b2,
                             unsigned char* __restrict__ ws) {
  int i = blockIdx.x * 256 + threadIdx.x;
  if (i < 524288) {                       // W1 [16][256][128] -> bf16 W1^T rows (h)
    int s = i >> 15, r = i & 32767, h = r >> 8, o = r & 255;
    float v = W1[(s * 256 + o) * 128 + h];
    *(unsigned short*)(ws + GATE_BYTES + s * S_IMG + h * S_W1_STRIDE + 2 * o) = f2bf(v);
  } else if (i < 589824) {                // W2 [16][128][32] -> f16 W2^T rows (a)
    int j = i - 524288, s = j >> 12, r = j & 4095, a = r >> 7, h = r & 127;
    float v = W2[(s * 128 + h) * 32 + a];
    *(_Float16*)(ws + GATE_BYTES + s * S_IMG + S_W2_OFF + a * S_W2_STRIDE + 2 * h) =
        (_Float16)v;
  } else if (i < 630784) {                // Wa1 [320][128] -> bf16 Wa1^T rows, XOR swz
    int j = i - 589824, h = j / 320, o = j - h * 320;
    float v = Wa1[o * 128 + h];
    *(unsigned short*)(ws + GATE_W1_OFF + h * 640 +
                       ((2 * o) ^ ((h & 7) << 4))) = f2bf(v);
  } else if (i < 632832) {                // Wa2 [128][16] -> f16 Wa2^T rows, XOR swz
    int j = i - 630784, n = j >> 7, h = j & 127;
    float v = Wa2[h * 16 + n];
    *(_Float16*)(ws + GATE_W2_OFF + n * 256 +
                 ((2 * h) ^ ((n & 7) << 3))) = (_Float16)v;
  } else if (i < 634880) {                // b1 [16][128] f32
    int j = i - 632832, s = j >> 7, h = j & 127;
    *(float*)(ws + GATE_BYTES + s * S_IMG + S_B1_OFF + 4 * h) = b1[s * 128 + h];
  } else if (i < 635392) {                // b2 [16][32] f32
    int j = i - 634880, s = j >> 5, a = j & 31;
    *(float*)(ws + GATE_BYTES + s * S_IMG + S_B2_OFF + 4 * a) = b2[s * 32 + a];
  } else if (i < 635520) {                // ba1 [128] f32
    int j = i - 635392;
    *(float*)(ws + GATE_BA1_OFF + 4 * j) = ba1[j];
  } else if (i < 635536) {                // ba2 [16] f32
    int j = i - 635520;
    *(float*)(ws + GATE_BA2_OFF + 4 * j) = ba2[j];
  }
}

__device__ __forceinline__ void stage_lin(const unsigned char* gsrc, unsigned char* ldst,
                                          int tid, int bytes) {
  for (int off = tid * 16; off < bytes; off += 512 * 16) {
    __builtin_amdgcn_global_load_lds(
        (const __attribute__((address_space(1))) unsigned int*)(const void*)(gsrc + off),
        (__attribute__((address_space(3))) unsigned int*)(void*)(ldst + off), 16, 0, 0);
  }
}

// ------------------------------- fused main ---------------------------------
// 256 blocks x 512 threads (8 waves), 1 block/CU, 256 rows/block.
// Wave pair (pr, pr+4): same 64 batch rows; half = wave>>2 picks h 0..63/64..127.
// launch_bounds(512,1): allocator freedom -> ~225 regs, no spill, 2 waves/SIMD.
__global__ __launch_bounds__(512, 1)
void mop_fused(const float* __restrict__ obs, const float* __restrict__ goals,
               const unsigned char* __restrict__ ws, float* __restrict__ dout) {
  extern __shared__ unsigned char smem[];
  const int tid  = threadIdx.x;
  const int lane = tid & 63;
  const int wave = tid >> 6;          // 0..7
  const int half = wave >> 2;         // h-half owner
  const int pr   = wave & 3;          // batch quarter (pair id)
  const int l15  = lane & 15;
  const int g    = lane >> 4;
  const int swz4 = (lane & 7) << 4;
  const int swz3 = (lane & 7) << 3;
  const int rowbase = blockIdx.x * 256 + pr * 64;

  float* out_mixed = dout;
  float* out_alpha = dout + 65536 * 32;

  // per-lane bases (wave's h-half folded in); ht' = 0..3, imm offsets in loop
  const int lw1 = half * 33792 + l15 * S_W1_STRIDE + 16 * g;         // + ht*8448 + t*64
  const int lw2 = S_W2_OFF + l15 * S_W2_STRIDE + 8 * g + half * 128; // + ta*4352 + ht*32
  const int lb1 = S_B1_OFF + 256 * half + 16 * g;                    // + ht*64
  const int lb2 = S_B2_OFF + 16 * g;                                 // + ta*64

  stage_lin(ws, smem, tid, GATE_BYTES);

  // obs B-fragments in regs: nb=4 -> 64 rows (pair waves duplicate-load; L2/L3 hit)
  bf16x8 obsf[4][8];
  #pragma unroll
  for (int nb = 0; nb < 4; ++nb) {
    const float* rp = obs + (size_t)(rowbase + nb * 16 + l15) * 256 + 8 * g;
    #pragma unroll
    for (int t = 0; t < 8; ++t) {
      f32x4 a = *(const f32x4*)(rp + 32 * t);
      f32x4 c = *(const f32x4*)(rp + 32 * t + 4);
      obsf[nb][t] = pack_bf8(a, c);
    }
  }

  const half2v zh = __builtin_amdgcn_cvt_pkrtz(0.f, 0.f);
  f32x4 lacc[4];
  {
    // goals scoped to the gate (freed after)
    bf16x8 goalf[4][2];
    #pragma unroll
    for (int nb = 0; nb < 4; ++nb) {
      const float* gp = goals + (size_t)(rowbase + nb * 16 + l15) * 64 + 8 * g;
      #pragma unroll
      for (int t = 0; t < 2; ++t) {
        f32x4 a = *(const f32x4*)(gp + 32 * t);
        f32x4 c = *(const f32x4*)(gp + 32 * t + 4);
        goalf[nb][t] = pack_bf8(a, c);
      }
    }

    __syncthreads();   // gate image resident
    // skill0 staging in flight during gate compute
    stage_lin(ws + GATE_BYTES, smem + GATE_BYTES, tid, S_IMG);

    // ---- gate in 2 passes of 2 nb-tiles (keeps gacc at 32 VGPR) ----
    #pragma unroll
    for (int p = 0; p < 2; ++p) {
      f32x4 gacc[2][4];
      #pragma unroll
      for (int ht = 0; ht < 4; ++ht) {
        f32x4 bias = *(const f32x4*)(smem + GATE_BA1_OFF + 256 * half + 64 * ht + 16 * g);
        gacc[0][ht] = bias; gacc[1][ht] = bias;
      }
      #pragma unroll
      for (int t = 0; t < 10; ++t) {
        bf16x8 bf0 = (t < 8) ? obsf[2 * p][t]     : goalf[2 * p][t - 8];
        bf16x8 bf1 = (t < 8) ? obsf[2 * p + 1][t] : goalf[2 * p + 1][t - 8];
        #pragma unroll
        for (int ht = 0; ht < 4; ++ht) {
          int row = 64 * half + 16 * ht + l15;
          bf16x8 af = *(const bf16x8*)(smem + GATE_W1_OFF + row * 640 +
                                       ((64 * t + 16 * g) ^ swz4));
          gacc[0][ht] = __builtin_amdgcn_mfma_f32_16x16x32_bf16(af, bf0, gacc[0][ht], 0, 0, 0);
          gacc[1][ht] = __builtin_amdgcn_mfma_f32_16x16x32_bf16(af, bf1, gacc[1][ht], 0, 0, 0);
        }
      }
      // layer-2 partial (split-K over h): this wave's 4 K-steps
      #pragma unroll
      for (int j = 0; j < 2; ++j) {
        const int nb = 2 * p + j;
        lacc[nb] = (half == 0) ? *(const f32x4*)(smem + GATE_BA2_OFF + 16 * g)
                               : f32x4{0.f, 0.f, 0.f, 0.f};
        #pragma unroll
        for (int ht = 0; ht < 4; ++ht) {
          f16x4 hf;
          RELU_PACK(hf, gacc[j][ht], zh);
          f16x4 wf = *(const f16x4*)(smem + GATE_W2_OFF + l15 * 256 +
                                     ((32 * (4 * half + ht) + 8 * g) ^ swz3));
          lacc[nb] = __builtin_amdgcn_mfma_f32_16x16x16f16(wf, hf, lacc[nb], 0, 0, 0);
        }
      }
    }
  }

  // ---- exchange logit partials across wave pair (scratch over gate W1 region) ----
  __syncthreads();   // all waves done reading gate weights
  #pragma unroll
  for (int nb = 0; nb < 4; ++nb)
    #pragma unroll
    for (int r = 0; r < 4; ++r)
      *(float*)(smem + wave * 4352 + nb * 1088 + (4 * g + r) * 68 + 4 * l15) = lacc[nb][r];
  __syncthreads();

  // alphas packed f16: pk[nb][j] holds (alpha_{4g+2j}, alpha_{4g+2j+1}) per lane
  half2v alph_pk[4][2];
  #pragma unroll
  for (int nb = 0; nb < 4; ++nb) {
    f32x4 l = lacc[nb];
    #pragma unroll
    for (int r = 0; r < 4; ++r)
      l[r] += *(const float*)(smem + (wave ^ 4) * 4352 + nb * 1088 + (4 * g + r) * 68 + 4 * l15);
    float m = fmaxf(fmaxf(l[0], l[1]), fmaxf(l[2], l[3]));
    m = fmaxf(m, __shfl_xor(m, 16, 64));
    m = fmaxf(m, __shfl_xor(m, 32, 64));
    f32x4 e;
    e[0] = __expf(l[0] - m); e[1] = __expf(l[1] - m);
    e[2] = __expf(l[2] - m); e[3] = __expf(l[3] - m);
    float ssum = e[0] + e[1] + e[2] + e[3];
    ssum += __shfl_xor(ssum, 16, 64);
    ssum += __shfl_xor(ssum, 32, 64);
    f32x4 al = e * (1.0f / ssum);
    if (half == 0)
      *(f32x4*)(out_alpha + (size_t)(rowbase + nb * 16 + l15) * 16 + 4 * g) = al;
    alph_pk[nb][0] = __builtin_amdgcn_cvt_pkrtz(al[0], al[1]);
    alph_pk[nb][1] = __builtin_amdgcn_cvt_pkrtz(al[2], al[3]);
  }

  __syncthreads();   // skill0 resident; scratch reads done before skill1 staging

  // ---- skill loop: wave computes its h-half (ht=0..3) for 64 batch rows ----
  f32x4 macc[4][2] = {};
  for (int s = 0; s < 16; ++s) {
    const unsigned char* buf = smem + ((s & 1) ? 0 : GATE_BYTES);
    if (s < 15) {
      unsigned char* nbuf = smem + (((s + 1) & 1) ? 0 : GATE_BYTES);
      stage_lin(ws + GATE_BYTES + (size_t)(s + 1) * S_IMG, nbuf, tid, S_IMG);
    }
    // alpha[s][row]: shfl the packed half2 from the holding lane, pick half by s&1
    const int asrc = ((s >> 2) << 4) | l15;
    float av[4];
    half2v ah[4];
    #pragma unroll
    for (int nb = 0; nb < 4; ++nb) {
      float pkf = __builtin_bit_cast(float, alph_pk[nb][(s >> 1) & 1]);
      half2v th = __builtin_bit_cast(half2v, __shfl(pkf, asrc, 64));
      auto sel = (s & 1) ? th[1] : th[0];
      half2v a2; a2[0] = sel; a2[1] = sel;
      ah[nb] = a2;
      av[nb] = (float)sel;
    }

    const unsigned char* w1p = buf + lw1;
    const unsigned char* w2p = buf + lw2;

    __builtin_amdgcn_s_setprio(1);
    #pragma unroll
    for (int ht = 0; ht < 4; ++ht) {
      f32x4 b1v = *(const f32x4*)(buf + lb1 + 64 * ht);
      f32x4 acc[4];
      #pragma unroll
      for (int nb = 0; nb < 4; ++nb) acc[nb] = b1v;
      #pragma unroll
      for (int t = 0; t < 8; ++t) {
        bf16x8 af = *(const bf16x8*)(w1p + ht * 8448 + t * 64);  // imm offsets
        #pragma unroll
        for (int nb = 0; nb < 4; ++nb)
          acc[nb] = __builtin_amdgcn_mfma_f32_16x16x32_bf16(af, obsf[nb][t], acc[nb], 0, 0, 0);
      }
      f16x4 hf[4];
      #pragma unroll
      for (int nb = 0; nb < 4; ++nb) RELU_SCALE_PACK(hf[nb], acc[nb], ah[nb], zh);
      #pragma unroll
      for (int ta = 0; ta < 2; ++ta) {
        f16x4 wf = *(const f16x4*)(w2p + ta * 4352 + ht * 32);   // imm offsets
        #pragma unroll
        for (int nb = 0; nb < 4; ++nb)
          macc[nb][ta] = __builtin_amdgcn_mfma_f32_16x16x16f16(wf, hf[nb], macc[nb][ta], 0, 0, 0);
      }
    }
    __builtin_amdgcn_s_setprio(0);
    if (half == 0) {   // bias term added once per output
      #pragma unroll
      for (int ta = 0; ta < 2; ++ta) {
        f32x4 b2v = *(const f32x4*)(buf + lb2 + 64 * ta);
        #pragma unroll
        for (int nb = 0; nb < 4; ++nb)
          macc[nb][ta] = macc[nb][ta] + b2v * av[nb];
      }
    }
    __syncthreads();   // drains next-skill stage + releases buf
  }

  // ---- combine split-K partial mixed across wave pairs, then store ----
  #pragma unroll
  for (int nb = 0; nb < 4; ++nb)
    #pragma unroll
    for (int ta = 0; ta < 2; ++ta)
      #pragma unroll
      for (int r = 0; r < 4; ++r)
        *(float*)(smem + wave * 8704 + nb * 2176 + (16 * ta + 4 * g + r) * 68 + 4 * l15) =
            macc[nb][ta][r];
  __syncthreads();
  #pragma unroll
  for (int j = 0; j < 2; ++j) {
    const int nb = 2 * half + j;   // each wave stores half the batch range
    #pragma unroll
    for (int ta = 0; ta < 2; ++ta) {
      f32x4 v = macc[nb][ta];
      #pragma unroll
      for (int r = 0; r < 4; ++r)
        v[r] += *(const float*)(smem + (wave ^ 4) * 8704 + nb * 2176 +
                                (16 * ta + 4 * g + r) * 68 + 4 * l15);
      *(f32x4*)(out_mixed + (size_t)(rowbase + nb * 16 + l15) * 32 + 16 * ta + 4 * g) = v;
    }
  }
}

extern "C" void kernel_launch(void* const* d_in, const int* in_sizes, int n_in,
                              void* d_out, int out_size, void* d_ws, size_t ws_size,
                              hipStream_t stream) {
  const float* obs   = (const float*)d_in[0];
  const float* goals = (const float*)d_in[1];
  const float* Wa1   = (const float*)d_in[2];
  const float* ba1   = (const float*)d_in[3];
  const float* Wa2   = (const float*)d_in[4];
  const float* ba2   = (const float*)d_in[5];
  const float* W1    = (const float*)d_in[6];
  const float* b1    = (const float*)d_in[7];
  const float* W2    = (const float*)d_in[8];
  const float* b2    = (const float*)d_in[9];
  unsigned char* ws  = (unsigned char*)d_ws;
  float* out = (float*)d_out;

  prep_weights<<<2483, 256, 0, stream>>>(Wa1, Wa2, ba1, ba2, W1, W2, b1, b2, ws);
  mop_fused<<<256, 512, LDS_BYTES, stream>>>(obs, goals, ws, out);
}

// Round 11
// 103.627 us; speedup vs baseline: 1.0512x; 1.0512x over previous
//
#include <hip/hip_runtime.h>

// MoP fused kernel for MI355X (gfx950).
// B=65536, OBS=256, GOAL=64, S=16, H=128, A=32.
// d_out = [mixed (B*32 f32)] ++ [alphas (B*16 f32)]
// R11: R10's M-split (wave pairs share 64 rows; halves of h) with a ~16-reg
// diet so the 256-reg budget at 2 waves/SIMD holds WITHOUT spill:
//   - alphas in an LDS table (dead gate-tail hole), not registers/shfl
//   - av[] recomputed in-branch; b2v scoped
// Plus ht-stagger: odd waves rotate the ht order by 2 so adjacent waves
// alternate LDS-burst vs MFMA-burst phases (R5-R10 showed additive pipes).

typedef __attribute__((ext_vector_type(8))) short    bf16x8;  // 8 bf16, 4 VGPR
typedef __attribute__((ext_vector_type(4))) float    f32x4;
typedef __attribute__((ext_vector_type(4))) _Float16 f16x4;
using half2v = decltype(__builtin_amdgcn_cvt_pkrtz(0.f, 0.f));  // __fp16 x2

// ---- gate image (XOR-swizzled W, one-time use) ----
#define GATE_W1_OFF   0        // Wa1^T bf16: 128 rows x 640 B = 81920
#define GATE_W2_OFF   81920    // Wa2^T f16: 16 rows x 256 B = 4096
#define GATE_BA1_OFF  86016    // ba1 f32[128] = 512
#define GATE_BA2_OFF  86528    // ba2 f32[16]  = 64
#define GATE_BYTES    86592
// ---- skill images (pad-based, immediate-offset reads) ----
#define S_W1_STRIDE   528      // 128 rows -> 67584 B
#define S_W2_OFF      67584    // 32 rows x 272 B = 8704
#define S_W2_STRIDE   272
#define S_B1_OFF      76288    // b1 f32[128] = 512
#define S_B2_OFF      76800    // b2 f32[32]  = 128
#define S_IMG         76928
// alpha table in the [bufA_end, GATE_BYTES) hole; written after gate reads done
#define ALPHA_TBL     76928    // [s][row]: s*544 + row*2 (f16), 16x544 = 8704 B
#define LDS_BYTES     163520   // bufA [0,76928) odd skills, bufB [86592,+76928) even

__device__ __forceinline__ unsigned short f2bf(float f) {
  unsigned u = __builtin_bit_cast(unsigned, f);
  return (unsigned short)((u + 0x7FFFu + ((u >> 16) & 1u)) >> 16);  // RNE
}

__device__ __forceinline__ bf16x8 pack_bf8(f32x4 a, f32x4 b) {
  int4 r;
  asm("v_cvt_pk_bf16_f32 %0, %1, %2" : "=v"(r.x) : "v"(a[0]), "v"(a[1]));
  asm("v_cvt_pk_bf16_f32 %0, %1, %2" : "=v"(r.y) : "v"(a[2]), "v"(a[3]));
  asm("v_cvt_pk_bf16_f32 %0, %1, %2" : "=v"(r.z) : "v"(b[0]), "v"(b[1]));
  asm("v_cvt_pk_bf16_f32 %0, %1, %2" : "=v"(r.w) : "v"(b[2]), "v"(b[3]));
  return __builtin_bit_cast(bf16x8, r);
}

#define RELU_SCALE_PACK(dst, v, av, z)                                   \
  {                                                                      \
    half2v lo_ = __builtin_amdgcn_cvt_pkrtz((v)[0], (v)[1]);             \
    half2v hi_ = __builtin_amdgcn_cvt_pkrtz((v)[2], (v)[3]);             \
    lo_ = __builtin_elementwise_max(lo_, z) * (av);                      \
    hi_ = __builtin_elementwise_max(hi_, z) * (av);                      \
    dst[0] = (_Float16)lo_[0]; dst[1] = (_Float16)lo_[1];                \
    dst[2] = (_Float16)hi_[0]; dst[3] = (_Float16)hi_[1];                \
  }
#define RELU_PACK(dst, v, z)                                             \
  {                                                                      \
    half2v lo_ = __builtin_amdgcn_cvt_pkrtz((v)[0], (v)[1]);             \
    half2v hi_ = __builtin_amdgcn_cvt_pkrtz((v)[2], (v)[3]);             \
    lo_ = __builtin_elementwise_max(lo_, z);                             \
    hi_ = __builtin_elementwise_max(hi_, z);                             \
    dst[0] = (_Float16)lo_[0]; dst[1] = (_Float16)lo_[1];                \
    dst[2] = (_Float16)hi_[0]; dst[3] = (_Float16)hi_[1];                \
  }

// ---------------- weight prep: f32 -> bf16/f16 LDS images in ws -------------
__global__ void prep_weights(const float* __restrict__ Wa1, const float* __restrict__ Wa2,
                             const float* __restrict__ ba1, const float* __restrict__ ba2,
                             const float* __restrict__ W1,  const float* __restrict__ W2,
                             const float* __restrict__ b1,  const float* __restrict__ b2,
                             unsigned char* __restrict__ ws) {
  int i = blockIdx.x * 256 + threadIdx.x;
  if (i < 524288) {                       // W1 [16][256][128] -> bf16 W1^T rows (h)
    int s = i >> 15, r = i & 32767, h = r >> 8, o = r & 255;
    float v = W1[(s * 256 + o) * 128 + h];
    *(unsigned short*)(ws + GATE_BYTES + s * S_IMG + h * S_W1_STRIDE + 2 * o) = f2bf(v);
  } else if (i < 589824) {                // W2 [16][128][32] -> f16 W2^T rows (a)
    int j = i - 524288, s = j >> 12, r = j & 4095, a = r >> 7, h = r & 127;
    float v = W2[(s * 128 + h) * 32 + a];
    *(_Float16*)(ws + GATE_BYTES + s * S_IMG + S_W2_OFF + a * S_W2_STRIDE + 2 * h) =
        (_Float16)v;
  } else if (i < 630784) {                // Wa1 [320][128] -> bf16 Wa1^T rows, XOR swz
    int j = i - 589824, h = j / 320, o = j - h * 320;
    float v = Wa1[o * 128 + h];
    *(unsigned short*)(ws + GATE_W1_OFF + h * 640 +
                       ((2 * o) ^ ((h & 7) << 4))) = f2bf(v);
  } else if (i < 632832) {                // Wa2 [128][16] -> f16 Wa2^T rows, XOR swz
    int j = i - 630784, n = j >> 7, h = j & 127;
    float v = Wa2[h * 16 + n];
    *(_Float16*)(ws + GATE_W2_OFF + n * 256 +
                 ((2 * h) ^ ((n & 7) << 3))) = (_Float16)v;
  } else if (i < 634880) {                // b1 [16][128] f32
    int j = i - 632832, s = j >> 7, h = j & 127;
    *(float*)(ws + GATE_BYTES + s * S_IMG + S_B1_OFF + 4 * h) = b1[s * 128 + h];
  } else if (i < 635392) {                // b2 [16][32] f32
    int j = i - 634880, s = j >> 5, a = j & 31;
    *(float*)(ws + GATE_BYTES + s * S_IMG + S_B2_OFF + 4 * a) = b2[s * 32 + a];
  } else if (i < 635520) {                // ba1 [128] f32
    int j = i - 635392;
    *(float*)(ws + GATE_BA1_OFF + 4 * j) = ba1[j];
  } else if (i < 635536) {                // ba2 [16] f32
    int j = i - 635520;
    *(float*)(ws + GATE_BA2_OFF + 4 * j) = ba2[j];
  }
}

__device__ __forceinline__ void stage_lin(const unsigned char* gsrc, unsigned char* ldst,
                                          int tid, int bytes) {
  for (int off = tid * 16; off < bytes; off += 512 * 16) {
    __builtin_amdgcn_global_load_lds(
        (const __attribute__((address_space(1))) unsigned int*)(const void*)(gsrc + off),
        (__attribute__((address_space(3))) unsigned int*)(void*)(ldst + off), 16, 0, 0);
  }
}

// ------------------------------- fused main ---------------------------------
// 256 blocks x 512 threads (8 waves, 2/SIMD), 1 block/CU, 256 rows/block.
// Wave pair (pr, pr+4): same 64 batch rows; half = wave>>2 picks h 0..63/64..127.
__global__ __launch_bounds__(512, 1)
void mop_fused(const float* __restrict__ obs, const float* __restrict__ goals,
               const unsigned char* __restrict__ ws, float* __restrict__ dout) {
  extern __shared__ unsigned char smem[];
  const int tid  = threadIdx.x;
  const int lane = tid & 63;
  const int wave = tid >> 6;          // 0..7
  const int half = wave >> 2;         // h-half owner
  const int pr   = wave & 3;          // batch quarter (pair id)
  const int l15  = lane & 15;
  const int g    = lane >> 4;
  const int swz4 = (lane & 7) << 4;
  const int swz3 = (lane & 7) << 3;
  const int htrot = (wave & 1) << 1;  // phase stagger: odd waves start at ht=2
  const int rowbase = blockIdx.x * 256 + pr * 64;

  float* out_mixed = dout;
  float* out_alpha = dout + 65536 * 32;

  // per-lane bases (wave's h-half folded in); ht = 0..3, imm offsets in loop
  const int lw1 = half * 33792 + l15 * S_W1_STRIDE + 16 * g;         // + ht*8448 + t*64
  const int lw2 = S_W2_OFF + l15 * S_W2_STRIDE + 8 * g + half * 128; // + ta*4352 + ht*32
  const int lb1 = S_B1_OFF + 256 * half + 16 * g;                    // + ht*64
  const int lb2 = S_B2_OFF + 16 * g;                                 // + ta*64
  const int lrow = pr * 64 + l15;                                    // + nb*16 (alpha row)

  stage_lin(ws, smem, tid, GATE_BYTES);

  // obs B-fragments in regs: nb=4 -> 64 rows (pair waves duplicate-load; L2/L3 hit)
  bf16x8 obsf[4][8];
  #pragma unroll
  for (int nb = 0; nb < 4; ++nb) {
    const float* rp = obs + (size_t)(rowbase + nb * 16 + l15) * 256 + 8 * g;
    #pragma unroll
    for (int t = 0; t < 8; ++t) {
      f32x4 a = *(const f32x4*)(rp + 32 * t);
      f32x4 c = *(const f32x4*)(rp + 32 * t + 4);
      obsf[nb][t] = pack_bf8(a, c);
    }
  }

  const half2v zh = __builtin_amdgcn_cvt_pkrtz(0.f, 0.f);
  f32x4 lacc[4];
  {
    // goals scoped to the gate (freed after)
    bf16x8 goalf[4][2];
    #pragma unroll
    for (int nb = 0; nb < 4; ++nb) {
      const float* gp = goals + (size_t)(rowbase + nb * 16 + l15) * 64 + 8 * g;
      #pragma unroll
      for (int t = 0; t < 2; ++t) {
        f32x4 a = *(const f32x4*)(gp + 32 * t);
        f32x4 c = *(const f32x4*)(gp + 32 * t + 4);
        goalf[nb][t] = pack_bf8(a, c);
      }
    }

    __syncthreads();   // gate image resident
    // skill0 staging in flight during gate compute
    stage_lin(ws + GATE_BYTES, smem + GATE_BYTES, tid, S_IMG);

    // ---- gate in 2 passes of 2 nb-tiles (keeps gacc at 32 VGPR) ----
    #pragma unroll
    for (int p = 0; p < 2; ++p) {
      f32x4 gacc[2][4];
      #pragma unroll
      for (int ht = 0; ht < 4; ++ht) {
        f32x4 bias = *(const f32x4*)(smem + GATE_BA1_OFF + 256 * half + 64 * ht + 16 * g);
        gacc[0][ht] = bias; gacc[1][ht] = bias;
      }
      #pragma unroll
      for (int t = 0; t < 10; ++t) {
        bf16x8 bf0 = (t < 8) ? obsf[2 * p][t]     : goalf[2 * p][t - 8];
        bf16x8 bf1 = (t < 8) ? obsf[2 * p + 1][t] : goalf[2 * p + 1][t - 8];
        #pragma unroll
        for (int ht = 0; ht < 4; ++ht) {
          int row = 64 * half + 16 * ht + l15;
          bf16x8 af = *(const bf16x8*)(smem + GATE_W1_OFF + row * 640 +
                                       ((64 * t + 16 * g) ^ swz4));
          gacc[0][ht] = __builtin_amdgcn_mfma_f32_16x16x32_bf16(af, bf0, gacc[0][ht], 0, 0, 0);
          gacc[1][ht] = __builtin_amdgcn_mfma_f32_16x16x32_bf16(af, bf1, gacc[1][ht], 0, 0, 0);
        }
      }
      // layer-2 partial (split-K over h): this wave's 4 K-steps
      #pragma unroll
      for (int j = 0; j < 2; ++j) {
        const int nb = 2 * p + j;
        lacc[nb] = (half == 0) ? *(const f32x4*)(smem + GATE_BA2_OFF + 16 * g)
                               : f32x4{0.f, 0.f, 0.f, 0.f};
        #pragma unroll
        for (int ht = 0; ht < 4; ++ht) {
          f16x4 hf;
          RELU_PACK(hf, gacc[j][ht], zh);
          f16x4 wf = *(const f16x4*)(smem + GATE_W2_OFF + l15 * 256 +
                                     ((32 * (4 * half + ht) + 8 * g) ^ swz3));
          lacc[nb] = __builtin_amdgcn_mfma_f32_16x16x16f16(wf, hf, lacc[nb], 0, 0, 0);
        }
      }
    }
  }

  // ---- exchange logit partials across wave pair (scratch over gate W1 region) ----
  __syncthreads();   // all waves done reading gate weights
  #pragma unroll
  for (int nb = 0; nb < 4; ++nb)
    #pragma unroll
    for (int r = 0; r < 4; ++r)
      *(float*)(smem + wave * 4352 + nb * 1088 + (4 * g + r) * 68 + 4 * l15) = lacc[nb][r];
  __syncthreads();

  // softmax; alphas -> LDS table (no registers kept)
  #pragma unroll
  for (int nb = 0; nb < 4; ++nb) {
    f32x4 l = lacc[nb];
    #pragma unroll
    for (int r = 0; r < 4; ++r)
      l[r] += *(const float*)(smem + (wave ^ 4) * 4352 + nb * 1088 + (4 * g + r) * 68 + 4 * l15);
    float m = fmaxf(fmaxf(l[0], l[1]), fmaxf(l[2], l[3]));
    m = fmaxf(m, __shfl_xor(m, 16, 64));
    m = fmaxf(m, __shfl_xor(m, 32, 64));
    f32x4 e;
    e[0] = __expf(l[0] - m); e[1] = __expf(l[1] - m);
    e[2] = __expf(l[2] - m); e[3] = __expf(l[3] - m);
    float ssum = e[0] + e[1] + e[2] + e[3];
    ssum += __shfl_xor(ssum, 16, 64);
    ssum += __shfl_xor(ssum, 32, 64);
    f32x4 al = e * (1.0f / ssum);
    if (half == 0) {
      *(f32x4*)(out_alpha + (size_t)(rowbase + nb * 16 + l15) * 16 + 4 * g) = al;
      // alpha table write: skill = 4g+r, row = lrow + nb*16 (each row written once)
      #pragma unroll
      for (int r = 0; r < 4; ++r)
        *(_Float16*)(smem + ALPHA_TBL + (4 * g + r) * 544 + (lrow + nb * 16) * 2) =
            (_Float16)al[r];
    }
  }

  __syncthreads();   // skill0 + alpha table resident

  // ---- skill loop: wave computes its h-half (ht=0..3) for 64 batch rows ----
  f32x4 macc[4][2] = {};
  for (int s = 0; s < 16; ++s) {
    const unsigned char* buf = smem + ((s & 1) ? 0 : GATE_BYTES);
    if (s < 15) {
      unsigned char* nbuf = smem + (((s + 1) & 1) ? 0 : GATE_BYTES);
      stage_lin(ws + GATE_BYTES + (size_t)(s + 1) * S_IMG, nbuf, tid, S_IMG);
    }
    // alpha from LDS table (4 tiny reads; replaces the 8-shfl chain)
    half2v ah[4];
    #pragma unroll
    for (int nb = 0; nb < 4; ++nb) {
      unsigned short raw = *(const unsigned short*)(
          smem + ALPHA_TBL + s * 544 + (lrow + nb * 16) * 2);
      __fp16 hv = __builtin_bit_cast(__fp16, raw);
      half2v a2; a2[0] = hv; a2[1] = hv;
      ah[nb] = a2;
    }

    const unsigned char* w1p = buf + lw1;
    const unsigned char* w2p = buf + lw2;

    __builtin_amdgcn_s_setprio(1);
    #pragma unroll
    for (int hti = 0; hti < 4; ++hti) {
      const int ht = (hti + htrot) & 3;   // stagger: odd waves offset by 2
      f32x4 b1v = *(const f32x4*)(buf + lb1 + 64 * ht);
      f32x4 acc[4];
      #pragma unroll
      for (int nb = 0; nb < 4; ++nb) acc[nb] = b1v;
      const unsigned char* w1h = w1p + ht * 8448;
      #pragma unroll
      for (int t = 0; t < 8; ++t) {
        bf16x8 af = *(const bf16x8*)(w1h + t * 64);   // imm offsets off w1h
        #pragma unroll
        for (int nb = 0; nb < 4; ++nb)
          acc[nb] = __builtin_amdgcn_mfma_f32_16x16x32_bf16(af, obsf[nb][t], acc[nb], 0, 0, 0);
      }
      f16x4 hf[4];
      #pragma unroll
      for (int nb = 0; nb < 4; ++nb) RELU_SCALE_PACK(hf[nb], acc[nb], ah[nb], zh);
      #pragma unroll
      for (int ta = 0; ta < 2; ++ta) {
        f16x4 wf = *(const f16x4*)(w2p + ta * 4352 + ht * 32);
        #pragma unroll
        for (int nb = 0; nb < 4; ++nb)
          macc[nb][ta] = __builtin_amdgcn_mfma_f32_16x16x16f16(wf, hf[nb], macc[nb][ta], 0, 0, 0);
      }
    }
    __builtin_amdgcn_s_setprio(0);
    if (half == 0) {   // + alpha_s * b2[s], added once per output
      #pragma unroll
      for (int ta = 0; ta < 2; ++ta) {
        f32x4 b2v = *(const f32x4*)(buf + lb2 + 64 * ta);
        #pragma unroll
        for (int nb = 0; nb < 4; ++nb) {
          float av = (float)ah[nb][0];
          macc[nb][ta] = macc[nb][ta] + b2v * av;
        }
      }
    }
    __syncthreads();   // drains next-skill stage + releases buf
  }

  // ---- combine split-K partial mixed across wave pairs, then store ----
  #pragma unroll
  for (int nb = 0; nb < 4; ++nb)
    #pragma unroll
    for (int ta = 0; ta < 2; ++ta)
      #pragma unroll
      for (int r = 0; r < 4; ++r)
        *(float*)(smem + wave * 8704 + nb * 2176 + (16 * ta + 4 * g + r) * 68 + 4 * l15) =
            macc[nb][ta][r];
  __syncthreads();
  #pragma unroll
  for (int j = 0; j < 2; ++j) {
    const int nb = 2 * half + j;   // each wave stores half the batch range
    #pragma unroll
    for (int ta = 0; ta < 2; ++ta) {
      f32x4 v = macc[nb][ta];
      #pragma unroll
      for (int r = 0; r < 4; ++r)
        v[r] += *(const float*)(smem + (wave ^ 4) * 8704 + nb * 2176 +
                                (16 * ta + 4 * g + r) * 68 + 4 * l15);
      *(f32x4*)(out_mixed + (size_t)(rowbase + nb * 16 + l15) * 32 + 16 * ta + 4 * g) = v;
    }
  }
}

extern "C" void kernel_launch(void* const* d_in, const int* in_sizes, int n_in,
                              void* d_out, int out_size, void* d_ws, size_t ws_size,
                              hipStream_t stream) {
  const float* obs   = (const float*)d_in[0];
  const float* goals = (const float*)d_in[1];
  const float* Wa1   = (const float*)d_in[2];
  const float* ba1   = (const float*)d_in[3];
  const float* Wa2   = (const float*)d_in[4];
  const float* ba2   = (const float*)d_in[5];
  const float* W1    = (const float*)d_in[6];
  const float* b1    = (const float*)d_in[7];
  const float* W2    = (const float*)d_in[8];
  const float* b2    = (const float*)d_in[9];
  unsigned char* ws  = (unsigned char*)d_ws;
  float* out = (float*)d_out;

  prep_weights<<<2483, 256, 0, stream>>>(Wa1, Wa2, ba1, ba2, W1, W2, b1, b2, ws);
  mop_fused<<<256, 512, LDS_BYTES, stream>>>(obs, goals, ws, out);
}

// Round 12
// 93.515 us; speedup vs baseline: 1.1649x; 1.1081x over previous
//
#include <hip/hip_runtime.h>

// MoP fused kernel for MI355X (gfx950).
// B=65536, OBS=256, GOAL=64, S=16, H=128, A=32.
// d_out = [mixed (B*32 f32)] ++ [alphas (B*16 f32)]
// R12: R5 (best: 95.9us, no spill) + skill-loop interchange: t-outer with
// acc[2][8] held across t -> 16 independent MFMA chains (spacing 2 -> 16).
// R5's ht-outer form stalled every MFMA on its accumulator's previous result
// (~18cyc exposed latency = the 38us MfmaUtil vs ~10us issue-rate gap).

typedef __attribute__((ext_vector_type(8))) short    bf16x8;  // 8 bf16, 4 VGPR
typedef __attribute__((ext_vector_type(4))) float    f32x4;
typedef __attribute__((ext_vector_type(4))) _Float16 f16x4;
using half2v = decltype(__builtin_amdgcn_cvt_pkrtz(0.f, 0.f));  // __fp16 x2

// ---- gate image (XOR-swizzled W, one-time use) ----
#define GATE_W1_OFF   0        // Wa1^T bf16: 128 rows x 640 B = 81920
#define GATE_W2_OFF   81920    // Wa2^T f16: 16 rows x 256 B = 4096
#define GATE_BA1_OFF  86016    // ba1 f32[128] = 512
#define GATE_BA2_OFF  86528    // ba2 f32[16]  = 64
#define GATE_BYTES    86592
// ---- skill images (pad-based, immediate-offset reads) ----
#define S_W1_STRIDE   528      // 128 rows -> 67584 B
#define S_W2_OFF      67584    // 32 rows x 272 B = 8704
#define S_W2_STRIDE   272
#define S_B1_OFF      76288    // b1 f32[128] = 512
#define S_B2_OFF      76800    // b2 f32[32]  = 128
#define S_IMG         76928
#define LDS_BYTES     163520   // bufA [0,86592) gate/odd skills, bufB [86592,+76928) even

__device__ __forceinline__ unsigned short f2bf(float f) {
  unsigned u = __builtin_bit_cast(unsigned, f);
  return (unsigned short)((u + 0x7FFFu + ((u >> 16) & 1u)) >> 16);  // RNE
}

__device__ __forceinline__ bf16x8 pack_bf8(f32x4 a, f32x4 b) {
  int4 r;
  asm("v_cvt_pk_bf16_f32 %0, %1, %2" : "=v"(r.x) : "v"(a[0]), "v"(a[1]));
  asm("v_cvt_pk_bf16_f32 %0, %1, %2" : "=v"(r.y) : "v"(a[2]), "v"(a[3]));
  asm("v_cvt_pk_bf16_f32 %0, %1, %2" : "=v"(r.z) : "v"(b[0]), "v"(b[1]));
  asm("v_cvt_pk_bf16_f32 %0, %1, %2" : "=v"(r.w) : "v"(b[2]), "v"(b[3]));
  return __builtin_bit_cast(bf16x8, r);
}

#define RELU_SCALE_PACK(dst, v, av, z)                                   \
  {                                                                      \
    half2v lo_ = __builtin_amdgcn_cvt_pkrtz((v)[0], (v)[1]);             \
    half2v hi_ = __builtin_amdgcn_cvt_pkrtz((v)[2], (v)[3]);             \
    lo_ = __builtin_elementwise_max(lo_, z) * (av);                      \
    hi_ = __builtin_elementwise_max(hi_, z) * (av);                      \
    dst[0] = (_Float16)lo_[0]; dst[1] = (_Float16)lo_[1];                \
    dst[2] = (_Float16)hi_[0]; dst[3] = (_Float16)hi_[1];                \
  }

// ---------------- weight prep: f32 -> bf16/f16 LDS images in ws -------------
__global__ void prep_weights(const float* __restrict__ Wa1, const float* __restrict__ Wa2,
                             const float* __restrict__ ba1, const float* __restrict__ ba2,
                             const float* __restrict__ W1,  const float* __restrict__ W2,
                             const float* __restrict__ b1,  const float* __restrict__ b2,
                             unsigned char* __restrict__ ws) {
  int i = blockIdx.x * 256 + threadIdx.x;
  if (i < 524288) {                       // W1 [16][256][128] -> bf16 W1^T rows (h)
    int s = i >> 15, r = i & 32767, h = r >> 8, o = r & 255;
    float v = W1[(s * 256 + o) * 128 + h];
    *(unsigned short*)(ws + GATE_BYTES + s * S_IMG + h * S_W1_STRIDE + 2 * o) = f2bf(v);
  } else if (i < 589824) {                // W2 [16][128][32] -> f16 W2^T rows (a)
    int j = i - 524288, s = j >> 12, r = j & 4095, a = r >> 7, h = r & 127;
    float v = W2[(s * 128 + h) * 32 + a];
    *(_Float16*)(ws + GATE_BYTES + s * S_IMG + S_W2_OFF + a * S_W2_STRIDE + 2 * h) =
        (_Float16)v;
  } else if (i < 630784) {                // Wa1 [320][128] -> bf16 Wa1^T rows, XOR swz
    int j = i - 589824, h = j / 320, o = j - h * 320;
    float v = Wa1[o * 128 + h];
    *(unsigned short*)(ws + GATE_W1_OFF + h * 640 +
                       ((2 * o) ^ ((h & 7) << 4))) = f2bf(v);
  } else if (i < 632832) {                // Wa2 [128][16] -> f16 Wa2^T rows, XOR swz
    int j = i - 630784, n = j >> 7, h = j & 127;
    float v = Wa2[h * 16 + n];
    *(_Float16*)(ws + GATE_W2_OFF + n * 256 +
                 ((2 * h) ^ ((n & 7) << 3))) = (_Float16)v;
  } else if (i < 634880) {                // b1 [16][128] f32
    int j = i - 632832, s = j >> 7, h = j & 127;
    *(float*)(ws + GATE_BYTES + s * S_IMG + S_B1_OFF + 4 * h) = b1[s * 128 + h];
  } else if (i < 635392) {                // b2 [16][32] f32
    int j = i - 634880, s = j >> 5, a = j & 31;
    *(float*)(ws + GATE_BYTES + s * S_IMG + S_B2_OFF + 4 * a) = b2[s * 32 + a];
  } else if (i < 635520) {                // ba1 [128] f32
    int j = i - 635392;
    *(float*)(ws + GATE_BA1_OFF + 4 * j) = ba1[j];
  } else if (i < 635536) {                // ba2 [16] f32
    int j = i - 635520;
    *(float*)(ws + GATE_BA2_OFF + 4 * j) = ba2[j];
  }
}

__device__ __forceinline__ void stage_lin(const unsigned char* gsrc, unsigned char* ldst,
                                          int tid, int bytes) {
  for (int off = tid * 16; off < bytes; off += 512 * 16) {
    __builtin_amdgcn_global_load_lds(
        (const __attribute__((address_space(1))) unsigned int*)(const void*)(gsrc + off),
        (__attribute__((address_space(3))) unsigned int*)(void*)(ldst + off), 16, 0, 0);
  }
}

// ------------------------------- fused main ---------------------------------
// 256 blocks x 512 threads (8 waves, 2/SIMD), 1 block/CU, 256 batch rows/block,
// 32 rows per wave (nb=2).
__global__ __launch_bounds__(512, 2)
void mop_fused(const float* __restrict__ obs, const float* __restrict__ goals,
               const unsigned char* __restrict__ ws, float* __restrict__ dout) {
  extern __shared__ unsigned char smem[];
  const int tid  = threadIdx.x;
  const int lane = tid & 63;
  const int wave = tid >> 6;          // 0..7
  const int l15  = lane & 15;
  const int g    = lane >> 4;
  const int swz4 = (lane & 7) << 4;   // gate W1 swizzle (row&7 == l15&7)
  const int swz3 = (lane & 7) << 3;   // gate W2 swizzle
  const int rowbase = blockIdx.x * 256 + wave * 32;

  float* out_mixed = dout;
  float* out_alpha = dout + 65536 * 32;

  // per-lane skill-image base offsets (within an image)
  const int lw1 = l15 * S_W1_STRIDE + 16 * g;           // + ht*8448 + t*64 (imm)
  const int lw2 = S_W2_OFF + l15 * S_W2_STRIDE + 8 * g; // + ta*4352 + ht*32 (imm)
  const int lb  = 16 * g;                               // bias broadcast base

  // stage gate image into bufA (skill0 staged after barrier, overlaps gate compute)
  stage_lin(ws, smem, tid, GATE_BYTES);

  // obs/goals B-fragments in registers (B-frag: n = l15, k = 8g+j contiguous)
  bf16x8 obsf[2][8];
  bf16x8 goalf[2][2];
  #pragma unroll
  for (int nb = 0; nb < 2; ++nb) {
    const float* rp = obs + (size_t)(rowbase + nb * 16 + l15) * 256 + 8 * g;
    #pragma unroll
    for (int t = 0; t < 8; ++t) {
      f32x4 a = *(const f32x4*)(rp + 32 * t);
      f32x4 c = *(const f32x4*)(rp + 32 * t + 4);
      obsf[nb][t] = pack_bf8(a, c);
    }
    const float* gp = goals + (size_t)(rowbase + nb * 16 + l15) * 64 + 8 * g;
    #pragma unroll
    for (int t = 0; t < 2; ++t) {
      f32x4 a = *(const f32x4*)(gp + 32 * t);
      f32x4 c = *(const f32x4*)(gp + 32 * t + 4);
      goalf[nb][t] = pack_bf8(a, c);
    }
  }

  __syncthreads();   // gate image resident

  // skill0 staging in flight during gate compute; post-gate barrier drains it
  stage_lin(ws + GATE_BYTES, smem + GATE_BYTES, tid, S_IMG);

  // ---- gate layer 1: ha^T = Wa1^T x concat^T  (K = 320, 10 ksteps) ----
  f32x4 gacc[2][8];
  #pragma unroll
  for (int ht = 0; ht < 8; ++ht) {
    f32x4 bias = *(const f32x4*)(smem + GATE_BA1_OFF + 64 * ht + lb);
    gacc[0][ht] = bias; gacc[1][ht] = bias;
  }
  #pragma unroll
  for (int t = 0; t < 10; ++t) {
    bf16x8 bf0 = (t < 8) ? obsf[0][t] : goalf[0][t - 8];
    bf16x8 bf1 = (t < 8) ? obsf[1][t] : goalf[1][t - 8];
    #pragma unroll
    for (int ht = 0; ht < 8; ++ht) {
      int row = 16 * ht + l15;
      bf16x8 af = *(const bf16x8*)(smem + GATE_W1_OFF + row * 640 +
                                   ((64 * t + 16 * g) ^ swz4));
      gacc[0][ht] = __builtin_amdgcn_mfma_f32_16x16x32_bf16(af, bf0, gacc[0][ht], 0, 0, 0);
      gacc[1][ht] = __builtin_amdgcn_mfma_f32_16x16x32_bf16(af, bf1, gacc[1][ht], 0, 0, 0);
    }
  }

  // ---- gate layer 2 + softmax; C-layout feeds mfma16 B-frag directly ----
  const half2v zh = __builtin_amdgcn_cvt_pkrtz(0.f, 0.f);
  f32x4 alph[2];
  #pragma unroll
  for (int nb = 0; nb < 2; ++nb) {
    f32x4 lacc = *(const f32x4*)(smem + GATE_BA2_OFF + lb);
    #pragma unroll
    for (int ht = 0; ht < 8; ++ht) {
      f32x4 v = gacc[nb][ht];
      f16x4 hf;
      {
        half2v lo_ = __builtin_amdgcn_cvt_pkrtz(v[0], v[1]);
        half2v hi_ = __builtin_amdgcn_cvt_pkrtz(v[2], v[3]);
        lo_ = __builtin_elementwise_max(lo_, zh);
        hi_ = __builtin_elementwise_max(hi_, zh);
        hf[0] = (_Float16)lo_[0]; hf[1] = (_Float16)lo_[1];
        hf[2] = (_Float16)hi_[0]; hf[3] = (_Float16)hi_[1];
      }
      f16x4 wf = *(const f16x4*)(smem + GATE_W2_OFF + l15 * 256 +
                                 ((32 * ht + 8 * g) ^ swz3));
      lacc = __builtin_amdgcn_mfma_f32_16x16x16f16(wf, hf, lacc, 0, 0, 0);
    }
    // softmax over 16 logits: 4 regs here x lanes {l, l^16, l^32, l^48}
    float m = fmaxf(fmaxf(lacc[0], lacc[1]), fmaxf(lacc[2], lacc[3]));
    m = fmaxf(m, __shfl_xor(m, 16, 64));
    m = fmaxf(m, __shfl_xor(m, 32, 64));
    f32x4 e;
    e[0] = __expf(lacc[0] - m); e[1] = __expf(lacc[1] - m);
    e[2] = __expf(lacc[2] - m); e[3] = __expf(lacc[3] - m);
    float ssum = e[0] + e[1] + e[2] + e[3];
    ssum += __shfl_xor(ssum, 16, 64);
    ssum += __shfl_xor(ssum, 32, 64);
    float inv = 1.0f / ssum;
    alph[nb] = e * inv;
    *(f32x4*)(out_alpha + (size_t)(rowbase + nb * 16 + l15) * 16 + 4 * g) = alph[nb];
  }

  __syncthreads();   // skill0 resident; all waves done with gate LDS region

  // ---- skill loop: double-buffered staging, alpha folded into h ----
  // t-OUTER / acc[2][8]-inner: 16 independent MFMA chains, spacing 16.
  f32x4 macc[2][2] = {};
  for (int s = 0; s < 16; ++s) {
    const unsigned char* buf = smem + ((s & 1) ? 0 : GATE_BYTES);
    if (s < 15) {
      unsigned char* nbuf = smem + (((s + 1) & 1) ? 0 : GATE_BYTES);
      stage_lin(ws + GATE_BYTES + (size_t)(s + 1) * S_IMG, nbuf, tid, S_IMG);
    }
    // biases from the staged image (broadcast ds_read)
    f32x4 acc[2][8];
    #pragma unroll
    for (int ht = 0; ht < 8; ++ht) {
      f32x4 b1v = *(const f32x4*)(buf + S_B1_OFF + 64 * ht + lb);
      acc[0][ht] = b1v; acc[1][ht] = b1v;
    }

    // alpha[s][batch=l15] via component-select + shfl from the holding lane
    const int asrc = ((s >> 2) << 4) | l15;
    float p0 = (s & 1) ? alph[0][1] : alph[0][0];
    float p1 = (s & 1) ? alph[0][3] : alph[0][2];
    float as0 = __shfl((s & 2) ? p1 : p0, asrc, 64);
    float q0 = (s & 1) ? alph[1][1] : alph[1][0];
    float q1 = (s & 1) ? alph[1][3] : alph[1][2];
    float as1 = __shfl((s & 2) ? q1 : q0, asrc, 64);
    const half2v a0h = __builtin_amdgcn_cvt_pkrtz(as0, as0);
    const half2v a1h = __builtin_amdgcn_cvt_pkrtz(as1, as1);

    const unsigned char* w1p = buf + lw1;
    const unsigned char* w2p = buf + lw2;

    __builtin_amdgcn_s_setprio(1);
    // ---- layer 1: t outer, 16 independent accumulator chains ----
    #pragma unroll
    for (int t = 0; t < 8; ++t) {
      const unsigned char* w1t = w1p + t * 64;
      #pragma unroll
      for (int ht = 0; ht < 8; ++ht) {
        bf16x8 af = *(const bf16x8*)(w1t + ht * 8448);   // imm offsets
        acc[0][ht] = __builtin_amdgcn_mfma_f32_16x16x32_bf16(af, obsf[0][t], acc[0][ht], 0, 0, 0);
        acc[1][ht] = __builtin_amdgcn_mfma_f32_16x16x32_bf16(af, obsf[1][t], acc[1][ht], 0, 0, 0);
      }
    }
    // ---- epilogue: relu+alpha pack, layer 2 ----
    #pragma unroll
    for (int ht = 0; ht < 8; ++ht) {
      f16x4 hf0, hf1;
      RELU_SCALE_PACK(hf0, acc[0][ht], a0h, zh);
      RELU_SCALE_PACK(hf1, acc[1][ht], a1h, zh);
      #pragma unroll
      for (int ta = 0; ta < 2; ++ta) {
        f16x4 wf = *(const f16x4*)(w2p + ta * 4352 + ht * 32);   // imm offsets
        macc[0][ta] = __builtin_amdgcn_mfma_f32_16x16x16f16(wf, hf0, macc[0][ta], 0, 0, 0);
        macc[1][ta] = __builtin_amdgcn_mfma_f32_16x16x16f16(wf, hf1, macc[1][ta], 0, 0, 0);
      }
    }
    __builtin_amdgcn_s_setprio(0);
    // + alpha_s * b2[s]  (zeros in this test, kept for generality)
    #pragma unroll
    for (int ta = 0; ta < 2; ++ta) {
      f32x4 b2v = *(const f32x4*)(buf + S_B2_OFF + 64 * ta + lb);
      macc[0][ta] = macc[0][ta] + b2v * as0;
      macc[1][ta] = macc[1][ta] + b2v * as1;
    }
    __syncthreads();   // drains next-skill stage (vmcnt) + releases buf
  }

  // ---- store mixed: C-layout -> row (a) = 4g+r contiguous => float4 stores ----
  #pragma unroll
  for (int nb = 0; nb < 2; ++nb) {
    #pragma unroll
    for (int ta = 0; ta < 2; ++ta) {
      *(f32x4*)(out_mixed + (size_t)(rowbase + nb * 16 + l15) * 32 + 16 * ta + 4 * g) =
          macc[nb][ta];
    }
  }
}

extern "C" void kernel_launch(void* const* d_in, const int* in_sizes, int n_in,
                              void* d_out, int out_size, void* d_ws, size_t ws_size,
                              hipStream_t stream) {
  const float* obs   = (const float*)d_in[0];
  const float* goals = (const float*)d_in[1];
  const float* Wa1   = (const float*)d_in[2];
  const float* ba1   = (const float*)d_in[3];
  const float* Wa2   = (const float*)d_in[4];
  const float* ba2   = (const float*)d_in[5];
  const float* W1    = (const float*)d_in[6];
  const float* b1    = (const float*)d_in[7];
  const float* W2    = (const float*)d_in[8];
  const float* b2    = (const float*)d_in[9];
  unsigned char* ws  = (unsigned char*)d_ws;
  float* out = (float*)d_out;

  prep_weights<<<2483, 256, 0, stream>>>(Wa1, Wa2, ba1, ba2, W1, W2, b1, b2, ws);
  mop_fused<<<256, 512, LDS_BYTES, stream>>>(obs, goals, ws, out);
}